// Round 4
// baseline (966.214 us; speedup 1.0000x reference)
//
#include <hip/hip_runtime.h>

// Problem constants
#define NITEMS 50000
#define EMBD   16
#define NSLATE 10
#define HIDD   512
#define LATD   64
#define RESPD  1024
#define BATCH  256
#define NCHUNK 8
#define CHUNK  6250   // NITEMS / NCHUNK; 6250 = 24*256 + 106
#define LOG2E  1.44269504088896340736f
#define SHIFT  64.0f  // fixed log2-domain shift: s = sum exp2(x*log2e - 64)

// d_out layout (float): z_mean[256*64] | z_log_var[256*64] | recon_slate[256*10] | recon_resp[256*10]
#define OUT_ZM 0
#define OUT_ZLV 16384
#define OUT_RS 32768
#define OUT_RR 35328

// ws layout (floats):
#define WS_X    0        // 256*1200 = 307200
#define WS_DZ   307200   // 256*1104 = 282624
#define WS_RX   589824   // 40960 (pre-scaled by LOG2E)
#define WS_PART 630784   // 4*256*512 = 524288 (split-K partials, reused enc/d1)
#define WS_SPS  1155072  // 256*8*10 = 20480
#define WS_SPM  1175552  // 20480
#define WS_SPA  1196032  // 20480 (int)
// total 1216512 floats = 4.87 MB

// Fused: ragged mean-pool (per batch row) + build x and dz conditional parts.
// One block per b; no atomics, no zero pass.
__global__ __launch_bounds__(256) void pool_build(const int* __restrict__ u,
    const int* __restrict__ slate, const float* __restrict__ resp,
    const float* __restrict__ emb, float* __restrict__ x, float* __restrict__ dz) {
  __shared__ float red[4][17];
  __shared__ float fin[17];
  int b = blockIdx.x, t = threadIdx.x;
  float acc[16];
  #pragma unroll
  for (int i = 0; i < 16; ++i) acc[i] = 0.0f;
  float c = 0.0f;
  const int* ub = u + (size_t)b * NITEMS;
  for (int n = t; n < NITEMS; n += 256) {
    if (ub[n]) {
      const float4* e4 = (const float4*)(emb + (size_t)n * 16);
      float4 a = e4[0], bb = e4[1], cc = e4[2], dd = e4[3];
      acc[0] += a.x;  acc[1] += a.y;  acc[2] += a.z;  acc[3] += a.w;
      acc[4] += bb.x; acc[5] += bb.y; acc[6] += bb.z; acc[7] += bb.w;
      acc[8] += cc.x; acc[9] += cc.y; acc[10] += cc.z; acc[11] += cc.w;
      acc[12] += dd.x; acc[13] += dd.y; acc[14] += dd.z; acc[15] += dd.w;
      c += 1.0f;
    }
  }
  #pragma unroll
  for (int off = 32; off > 0; off >>= 1) {
    #pragma unroll
    for (int i = 0; i < 16; ++i) acc[i] += __shfl_down(acc[i], off);
    c += __shfl_down(c, off);
  }
  int lane = t & 63, wv = t >> 6;
  if (lane == 0) {
    #pragma unroll
    for (int i = 0; i < 16; ++i) red[wv][i] = acc[i];
    red[wv][16] = c;
  }
  __syncthreads();
  if (t < 17) fin[t] = red[0][t] + red[1][t] + red[2][t] + red[3][t];
  __syncthreads();
  float inv = 1.0f / fin[16];
  if (t < 16) {
    float uv = fin[t] * inv;
    x[b * 1200 + 160 + t] = uv;
    dz[b * 1104 + 64 + t] = uv;
  }
  if (t >= 32 && t < 192) {
    int i = t - 32;
    int k = i >> 4, e = i & 15;
    int it = slate[b * 10 + k];
    x[b * 1200 + i] = emb[(size_t)it * 16 + e];
  }
  for (int i = t; i < 1024; i += 256) {
    float r = resp[b * 1024 + i];
    x[b * 1200 + 176 + i] = r;
    dz[b * 1104 + 80 + i] = r;
  }
}

// Split-K partial GEMM: P[z][M,N] = A[M,ks:ke] @ B[N,ks:ke]^T
// 64x64 tile, 256 threads, 4x4 microtile, BK=16.
__global__ __launch_bounds__(256) void gemm64(const float* __restrict__ A,
    const float* __restrict__ B, float* __restrict__ P, int M, int N, int K, int kChunk) {
  __shared__ float As[16][68];  // As[kk][m]
  __shared__ float Bs[16][68];  // Bs[kk][n]
  int tid = threadIdx.x;
  int m0 = blockIdx.y * 64, n0 = blockIdx.x * 64;
  int ks = blockIdx.z * kChunk;
  int ke = ks + kChunk; if (ke > K) ke = K;
  int sr = tid >> 2;          // 0..63
  int sc = (tid & 3) * 4;     // 0,4,8,12
  int tx = tid & 15, ty = tid >> 4;
  float acc[4][4];
  #pragma unroll
  for (int i = 0; i < 4; ++i)
    #pragma unroll
    for (int j = 0; j < 4; ++j) acc[i][j] = 0.f;
  for (int k0 = ks; k0 < ke; k0 += 16) {
    float4 av = make_float4(0.f, 0.f, 0.f, 0.f);
    float4 bv = make_float4(0.f, 0.f, 0.f, 0.f);
    if (k0 + sc < ke)
      av = *(const float4*)(A + (size_t)(m0 + sr) * K + k0 + sc);
    if (k0 + sc < ke && n0 + sr < N)
      bv = *(const float4*)(B + (size_t)(n0 + sr) * K + k0 + sc);
    __syncthreads();
    As[sc][sr] = av.x; As[sc + 1][sr] = av.y; As[sc + 2][sr] = av.z; As[sc + 3][sr] = av.w;
    Bs[sc][sr] = bv.x; Bs[sc + 1][sr] = bv.y; Bs[sc + 2][sr] = bv.z; Bs[sc + 3][sr] = bv.w;
    __syncthreads();
    #pragma unroll
    for (int kk = 0; kk < 16; ++kk) {
      float4 a4 = *(const float4*)&As[kk][4 * ty];
      float4 b4 = *(const float4*)&Bs[kk][4 * tx];
      float a[4] = {a4.x, a4.y, a4.z, a4.w};
      float b[4] = {b4.x, b4.y, b4.z, b4.w};
      #pragma unroll
      for (int i = 0; i < 4; ++i)
        #pragma unroll
        for (int j = 0; j < 4; ++j) acc[i][j] = fmaf(a[i], b[j], acc[i][j]);
    }
  }
  float* Pz = P + (size_t)blockIdx.z * M * N;
  #pragma unroll
  for (int i = 0; i < 4; ++i) {
    int m = m0 + 4 * ty + i, n = n0 + 4 * tx;
    if (n < N)
      *(float4*)(Pz + (size_t)m * N + n) = make_float4(acc[i][0], acc[i][1], acc[i][2], acc[i][3]);
  }
}

// h = relu(sum_s part[s] + b_enc); z_mean/z_log_var -> out; z -> dz[0:64]
__global__ __launch_bounds__(128) void mulv_z_kernel(const float* __restrict__ part,
    const float* __restrict__ benc,
    const float* __restrict__ Wmu, const float* __restrict__ bmu,
    const float* __restrict__ Wlv, const float* __restrict__ blv,
    const float* __restrict__ eps, float* __restrict__ out, float* __restrict__ dz) {
  __shared__ __align__(16) float hs[512];
  __shared__ float zms[64], zlvs[64];
  int b = blockIdx.x, t = threadIdx.x;
  for (int i = t; i < 512; i += 128) {
    float a = benc[i];
    #pragma unroll
    for (int s = 0; s < 4; ++s) a += part[(size_t)s * 131072 + b * 512 + i];
    hs[i] = fmaxf(a, 0.f);
  }
  __syncthreads();
  const float* Wr = (t < 64) ? (Wmu + (size_t)t * 512) : (Wlv + (size_t)(t - 64) * 512);
  float bias = (t < 64) ? bmu[t] : blv[t - 64];
  const float4* w4 = (const float4*)Wr;
  const float4* h4 = (const float4*)hs;
  float a0 = 0.f, a1 = 0.f, a2 = 0.f, a3 = 0.f;
  #pragma unroll 4
  for (int i = 0; i < 128; ++i) {
    float4 w = w4[i], hv = h4[i];
    a0 = fmaf(w.x, hv.x, a0); a1 = fmaf(w.y, hv.y, a1);
    a2 = fmaf(w.z, hv.z, a2); a3 = fmaf(w.w, hv.w, a3);
  }
  float acc = (a0 + a1) + (a2 + a3) + bias;
  if (t < 64) { out[OUT_ZM + b * 64 + t] = acc; zms[t] = acc; }
  else        { out[OUT_ZLV + b * 64 + (t - 64)] = acc; zlvs[t - 64] = acc; }
  __syncthreads();
  if (t < 64) {
    float zv = fmaf(eps[b * 64 + t], __builtin_amdgcn_exp2f(0.7213475204444817f * zlvs[t]), zms[t]);
    dz[b * 1104 + t] = zv;
  }
}

// d2 GEMM with reduce-on-load: A[m][k] = relu(sum_s part[s][m*512+k] + b_d1[k]),
// C = A @ W_d2^T + b_d2, relu, scaled by LOG2E -> rx. M=256,N=160,K=512.
__global__ __launch_bounds__(256) void gemm_d2(const float* __restrict__ part,
    const float* __restrict__ bd1, const float* __restrict__ W,
    const float* __restrict__ bias, float* __restrict__ rx) {
  __shared__ float As[16][68];
  __shared__ float Bs[16][68];
  const int N = 160, K = 512;
  int tid = threadIdx.x;
  int m0 = blockIdx.y * 64, n0 = blockIdx.x * 64;
  int sr = tid >> 2, sc = (tid & 3) * 4;
  int tx = tid & 15, ty = tid >> 4;
  float acc[4][4];
  #pragma unroll
  for (int i = 0; i < 4; ++i)
    #pragma unroll
    for (int j = 0; j < 4; ++j) acc[i][j] = 0.f;
  for (int k0 = 0; k0 < K; k0 += 16) {
    int col = k0 + sc;
    const float* p = part + (size_t)(m0 + sr) * 512 + col;
    float4 a0 = *(const float4*)(p);
    float4 a1 = *(const float4*)(p + 131072);
    float4 a2 = *(const float4*)(p + 262144);
    float4 a3 = *(const float4*)(p + 393216);
    float4 bb = *(const float4*)(bd1 + col);
    float4 av;
    av.x = fmaxf(a0.x + a1.x + a2.x + a3.x + bb.x, 0.f);
    av.y = fmaxf(a0.y + a1.y + a2.y + a3.y + bb.y, 0.f);
    av.z = fmaxf(a0.z + a1.z + a2.z + a3.z + bb.z, 0.f);
    av.w = fmaxf(a0.w + a1.w + a2.w + a3.w + bb.w, 0.f);
    float4 bv = make_float4(0.f, 0.f, 0.f, 0.f);
    if (n0 + sr < N)
      bv = *(const float4*)(W + (size_t)(n0 + sr) * 512 + col);
    __syncthreads();
    As[sc][sr] = av.x; As[sc + 1][sr] = av.y; As[sc + 2][sr] = av.z; As[sc + 3][sr] = av.w;
    Bs[sc][sr] = bv.x; Bs[sc + 1][sr] = bv.y; Bs[sc + 2][sr] = bv.z; Bs[sc + 3][sr] = bv.w;
    __syncthreads();
    #pragma unroll
    for (int kk = 0; kk < 16; ++kk) {
      float4 a4 = *(const float4*)&As[kk][4 * ty];
      float4 b4 = *(const float4*)&Bs[kk][4 * tx];
      float a[4] = {a4.x, a4.y, a4.z, a4.w};
      float b[4] = {b4.x, b4.y, b4.z, b4.w};
      #pragma unroll
      for (int i = 0; i < 4; ++i)
        #pragma unroll
        for (int j = 0; j < 4; ++j) acc[i][j] = fmaf(a[i], b[j], acc[i][j]);
    }
  }
  #pragma unroll
  for (int i = 0; i < 4; ++i) {
    int m = m0 + 4 * ty + i, n = n0 + 4 * tx;
    if (n < N) {
      float4 v;
      v.x = fmaxf(acc[i][0] + bias[n], 0.f) * LOG2E;
      v.y = fmaxf(acc[i][1] + bias[n + 1], 0.f) * LOG2E;
      v.z = fmaxf(acc[i][2] + bias[n + 2], 0.f) * LOG2E;
      v.w = fmaxf(acc[i][3] + bias[n + 3], 0.f) * LOG2E;
      *(float4*)(rx + (size_t)m * 160 + n) = v;
    }
  }
}

// Per (b, chunk): fixed-shift softmax partials. rx pre-scaled by LOG2E.
// 4 items per macro-iter amortize rxs LDS reads 4x; s/m/am are independent chains.
__global__ __launch_bounds__(256, 3) void score_part(const float* __restrict__ rx,
    const float* __restrict__ emb, float* __restrict__ psg, float* __restrict__ pmg,
    int* __restrict__ pag) {
  __shared__ __align__(16) float rxs[160];
  __shared__ float wm[4][10], wsum[4][10];
  __shared__ int wa[4][10];
  int b = blockIdx.x, c = blockIdx.y, t = threadIdx.x;
  if (t < 160) rxs[t] = rx[b * 160 + t];
  __syncthreads();
  float m[10], s[10];
  int am[10];
  #pragma unroll
  for (int k = 0; k < 10; ++k) { m[k] = -3.402823466e38f; s[k] = 0.f; am[k] = 0; }
  int nBase = c * CHUNK;
  const float4* ep = (const float4*)emb;
  #pragma unroll 1
  for (int j = 0; j < 6; ++j) {
    int n0 = nBase + j * 1024 + t;
    float4 e[4][4];
    #pragma unroll
    for (int it = 0; it < 4; ++it) {
      const float4* p = ep + (size_t)(n0 + it * 256) * 4;
      e[it][0] = p[0]; e[it][1] = p[1]; e[it][2] = p[2]; e[it][3] = p[3];
    }
    #pragma unroll
    for (int k = 0; k < 10; ++k) {
      float4 r0 = *(const float4*)(rxs + k * 16);
      float4 r1 = *(const float4*)(rxs + k * 16 + 4);
      float4 r2 = *(const float4*)(rxs + k * 16 + 8);
      float4 r3 = *(const float4*)(rxs + k * 16 + 12);
      #pragma unroll
      for (int it = 0; it < 4; ++it) {
        float x0 = fmaf(e[it][0].x, r0.x, -SHIFT);
        float x1 = e[it][1].x * r1.x;
        float x2 = e[it][2].x * r2.x;
        float x3 = e[it][3].x * r3.x;
        x0 = fmaf(e[it][0].y, r0.y, x0);
        x1 = fmaf(e[it][1].y, r1.y, x1);
        x2 = fmaf(e[it][2].y, r2.y, x2);
        x3 = fmaf(e[it][3].y, r3.y, x3);
        x0 = fmaf(e[it][0].z, r0.z, x0);
        x1 = fmaf(e[it][1].z, r1.z, x1);
        x2 = fmaf(e[it][2].z, r2.z, x2);
        x3 = fmaf(e[it][3].z, r3.z, x3);
        x0 = fmaf(e[it][0].w, r0.w, x0);
        x1 = fmaf(e[it][1].w, r1.w, x1);
        x2 = fmaf(e[it][2].w, r2.w, x2);
        x3 = fmaf(e[it][3].w, r3.w, x3);
        float x = (x0 + x1) + (x2 + x3);
        s[k] += __builtin_amdgcn_exp2f(x);
        if (x > m[k]) { m[k] = x; am[k] = n0 + it * 256; }
      }
    }
  }
  // tail: 106 items
  if (t < CHUNK - 6144) {
    int n = nBase + 6144 + t;
    const float4* p = ep + (size_t)n * 4;
    float4 e0 = p[0], e1 = p[1], e2 = p[2], e3 = p[3];
    #pragma unroll
    for (int k = 0; k < 10; ++k) {
      const float4 r0 = *(const float4*)(rxs + k * 16);
      const float4 r1 = *(const float4*)(rxs + k * 16 + 4);
      const float4 r2 = *(const float4*)(rxs + k * 16 + 8);
      const float4 r3 = *(const float4*)(rxs + k * 16 + 12);
      float x0 = fmaf(e0.w, r0.w, fmaf(e0.z, r0.z, fmaf(e0.y, r0.y, fmaf(e0.x, r0.x, -SHIFT))));
      float x1 = fmaf(e1.w, r1.w, fmaf(e1.z, r1.z, fmaf(e1.y, r1.y, e1.x * r1.x)));
      float x2 = fmaf(e2.w, r2.w, fmaf(e2.z, r2.z, fmaf(e2.y, r2.y, e2.x * r2.x)));
      float x3 = fmaf(e3.w, r3.w, fmaf(e3.z, r3.z, fmaf(e3.y, r3.y, e3.x * r3.x)));
      float x = (x0 + x1) + (x2 + x3);
      s[k] += __builtin_amdgcn_exp2f(x);
      if (x > m[k]) { m[k] = x; am[k] = n; }
    }
  }
  // wave reduce: s sums; (m, am) argmax, lower index wins ties
  #pragma unroll
  for (int off = 32; off > 0; off >>= 1) {
    #pragma unroll
    for (int k = 0; k < 10; ++k) {
      s[k] += __shfl_down(s[k], off);
      float om = __shfl_down(m[k], off);
      int oa = __shfl_down(am[k], off);
      bool take = (om > m[k]) || (om == m[k] && oa < am[k]);
      am[k] = take ? oa : am[k];
      m[k] = fmaxf(m[k], om);
    }
  }
  int lane = t & 63, wv = t >> 6;
  if (lane == 0) {
    #pragma unroll
    for (int k = 0; k < 10; ++k) { wm[wv][k] = m[k]; wsum[wv][k] = s[k]; wa[wv][k] = am[k]; }
  }
  __syncthreads();
  if (t < 10) {
    int k = t;
    float M = wm[0][k], S = wsum[0][k];
    int AM = wa[0][k];
    #pragma unroll
    for (int w = 1; w < 4; ++w) {
      float m2 = wm[w][k];
      int oa = wa[w][k];
      bool take = (m2 > M) || (m2 == M && oa < AM);
      AM = take ? oa : AM;
      M = fmaxf(M, m2);
      S += wsum[w][k];
    }
    int idx = (b * NCHUNK + c) * 10 + k;
    psg[idx] = S; pmg[idx] = M; pag[idx] = AM;
  }
}

// Combine chunk partials: S adds (shared fixed shift); argmax; slate prob.
__global__ __launch_bounds__(256) void score_final(const float* __restrict__ psg,
    const float* __restrict__ pmg, const int* __restrict__ pag,
    const float* __restrict__ rx, const float* __restrict__ emb,
    const int* __restrict__ slate, float* __restrict__ out) {
  int tid = blockIdx.x * 256 + threadIdx.x;
  if (tid >= BATCH * 10) return;
  int b = tid / 10, k = tid % 10;
  int base = b * NCHUNK * 10 + k;
  float S = 0.f, M = -3.402823466e38f;
  int AM = 2147483647;
  #pragma unroll
  for (int c = 0; c < NCHUNK; ++c) {
    S += psg[base + c * 10];
    float m2 = pmg[base + c * 10];
    int oa = pag[base + c * 10];
    bool take = (m2 > M) || (m2 == M && oa < AM);
    AM = take ? oa : AM;
    M = fmaxf(M, m2);
  }
  int it = slate[b * 10 + k];
  const float* er = emb + (size_t)it * 16;
  const float* rr = rx + b * 160 + k * 16;
  float xs = -SHIFT;
  #pragma unroll
  for (int e = 0; e < 16; ++e) xs = fmaf(rr[e], er[e], xs);
  out[OUT_RS + b * 10 + k] = (float)AM;
  out[OUT_RR + b * 10 + k] = __builtin_amdgcn_exp2f(xs) / S;
}

extern "C" void kernel_launch(void* const* d_in, const int* in_sizes, int n_in,
                              void* d_out, int out_size, void* d_ws, size_t ws_size,
                              hipStream_t stream) {
  const int* user_repr = (const int*)d_in[0];
  const int* slate = (const int*)d_in[1];
  const float* resp = (const float*)d_in[2];
  const float* eps = (const float*)d_in[3];
  const float* emb = (const float*)d_in[4];
  const float* W_enc = (const float*)d_in[5];
  const float* b_enc = (const float*)d_in[6];
  const float* W_mu = (const float*)d_in[7];
  const float* b_mu = (const float*)d_in[8];
  const float* W_lv = (const float*)d_in[9];
  const float* b_lv = (const float*)d_in[10];
  const float* W_d1 = (const float*)d_in[11];
  const float* b_d1 = (const float*)d_in[12];
  const float* W_d2 = (const float*)d_in[13];
  const float* b_d2 = (const float*)d_in[14];
  float* out = (float*)d_out;
  float* ws = (float*)d_ws;

  float* x    = ws + WS_X;
  float* dz   = ws + WS_DZ;
  float* rx   = ws + WS_RX;
  float* part = ws + WS_PART;
  float* sps  = ws + WS_SPS;
  float* spm  = ws + WS_SPM;
  int*   spa  = (int*)(ws + WS_SPA);

  pool_build<<<256, 256, 0, stream>>>(user_repr, slate, resp, emb, x, dz);
  gemm64<<<dim3(8, 4, 4), 256, 0, stream>>>(x, W_enc, part, 256, 512, 1200, 300);
  mulv_z_kernel<<<256, 128, 0, stream>>>(part, b_enc, W_mu, b_mu, W_lv, b_lv, eps, out, dz);
  gemm64<<<dim3(8, 4, 4), 256, 0, stream>>>(dz, W_d1, part, 256, 512, 1104, 276);
  gemm_d2<<<dim3(3, 4), 256, 0, stream>>>(part, b_d1, W_d2, b_d2, rx);
  score_part<<<dim3(256, 8), 256, 0, stream>>>(rx, emb, sps, spm, spa);
  score_final<<<10, 256, 0, stream>>>(sps, spm, spa, rx, emb, slate, out);
}

// Round 5
// 423.889 us; speedup vs baseline: 2.2794x; 2.2794x over previous
//
#include <hip/hip_runtime.h>

// Problem constants
#define NITEMS 50000
#define EMBD   16
#define NSLATE 10
#define HIDD   512
#define LATD   64
#define RESPD  1024
#define BATCH  256
#define NCHUNK 8
#define CHUNK  6250   // NITEMS / NCHUNK; 6250 = 12*512 + 106
#define LOG2E  1.44269504088896340736f
#define SHIFT  64.0f  // fixed log2-domain shift: s = sum exp2(x*log2e - 64)

// d_out layout (float): z_mean[256*64] | z_log_var[256*64] | recon_slate[256*10] | recon_resp[256*10]
#define OUT_ZM 0
#define OUT_ZLV 16384
#define OUT_RS 32768
#define OUT_RR 35328

// ws layout (floats):
#define WS_X    0        // 256*1200 = 307200
#define WS_DZ   307200   // 256*1104 = 282624
#define WS_RX   589824   // 40960 (pre-scaled by LOG2E)
#define WS_PART 630784   // 4*256*512 = 524288 (split-K partials, reused enc/d1)
#define WS_SPS  1155072  // 256*8*10 = 20480
#define WS_SPM  1175552  // 20480
#define WS_SPA  1196032  // 20480 (int)
// total 1216512 floats = 4.87 MB

// Fused: ragged mean-pool (per batch row) + build x and dz conditional parts.
__global__ __launch_bounds__(256) void pool_build(const int* __restrict__ u,
    const int* __restrict__ slate, const float* __restrict__ resp,
    const float* __restrict__ emb, float* __restrict__ x, float* __restrict__ dz) {
  __shared__ float red[4][17];
  __shared__ float fin[17];
  int b = blockIdx.x, t = threadIdx.x;
  float acc[16];
  #pragma unroll
  for (int i = 0; i < 16; ++i) acc[i] = 0.0f;
  float c = 0.0f;
  const int* ub = u + (size_t)b * NITEMS;
  for (int n = t; n < NITEMS; n += 256) {
    if (ub[n]) {
      const float4* e4 = (const float4*)(emb + (size_t)n * 16);
      float4 a = e4[0], bb = e4[1], cc = e4[2], dd = e4[3];
      acc[0] += a.x;  acc[1] += a.y;  acc[2] += a.z;  acc[3] += a.w;
      acc[4] += bb.x; acc[5] += bb.y; acc[6] += bb.z; acc[7] += bb.w;
      acc[8] += cc.x; acc[9] += cc.y; acc[10] += cc.z; acc[11] += cc.w;
      acc[12] += dd.x; acc[13] += dd.y; acc[14] += dd.z; acc[15] += dd.w;
      c += 1.0f;
    }
  }
  #pragma unroll
  for (int off = 32; off > 0; off >>= 1) {
    #pragma unroll
    for (int i = 0; i < 16; ++i) acc[i] += __shfl_down(acc[i], off);
    c += __shfl_down(c, off);
  }
  int lane = t & 63, wv = t >> 6;
  if (lane == 0) {
    #pragma unroll
    for (int i = 0; i < 16; ++i) red[wv][i] = acc[i];
    red[wv][16] = c;
  }
  __syncthreads();
  if (t < 17) fin[t] = red[0][t] + red[1][t] + red[2][t] + red[3][t];
  __syncthreads();
  float inv = 1.0f / fin[16];
  if (t < 16) {
    float uv = fin[t] * inv;
    x[b * 1200 + 160 + t] = uv;
    dz[b * 1104 + 64 + t] = uv;
  }
  if (t >= 32 && t < 192) {
    int i = t - 32;
    int k = i >> 4, e = i & 15;
    int it = slate[b * 10 + k];
    x[b * 1200 + i] = emb[(size_t)it * 16 + e];
  }
  for (int i = t; i < 1024; i += 256) {
    float r = resp[b * 1024 + i];
    x[b * 1200 + 176 + i] = r;
    dz[b * 1104 + 80 + i] = r;
  }
}

// Split-K partial GEMM: P[z][M,N] = A[M,ks:ke] @ B[N,ks:ke]^T
__global__ __launch_bounds__(256) void gemm64(const float* __restrict__ A,
    const float* __restrict__ B, float* __restrict__ P, int M, int N, int K, int kChunk) {
  __shared__ float As[16][68];  // As[kk][m]
  __shared__ float Bs[16][68];  // Bs[kk][n]
  int tid = threadIdx.x;
  int m0 = blockIdx.y * 64, n0 = blockIdx.x * 64;
  int ks = blockIdx.z * kChunk;
  int ke = ks + kChunk; if (ke > K) ke = K;
  int sr = tid >> 2;          // 0..63
  int sc = (tid & 3) * 4;     // 0,4,8,12
  int tx = tid & 15, ty = tid >> 4;
  float acc[4][4];
  #pragma unroll
  for (int i = 0; i < 4; ++i)
    #pragma unroll
    for (int j = 0; j < 4; ++j) acc[i][j] = 0.f;
  for (int k0 = ks; k0 < ke; k0 += 16) {
    float4 av = make_float4(0.f, 0.f, 0.f, 0.f);
    float4 bv = make_float4(0.f, 0.f, 0.f, 0.f);
    if (k0 + sc < ke)
      av = *(const float4*)(A + (size_t)(m0 + sr) * K + k0 + sc);
    if (k0 + sc < ke && n0 + sr < N)
      bv = *(const float4*)(B + (size_t)(n0 + sr) * K + k0 + sc);
    __syncthreads();
    As[sc][sr] = av.x; As[sc + 1][sr] = av.y; As[sc + 2][sr] = av.z; As[sc + 3][sr] = av.w;
    Bs[sc][sr] = bv.x; Bs[sc + 1][sr] = bv.y; Bs[sc + 2][sr] = bv.z; Bs[sc + 3][sr] = bv.w;
    __syncthreads();
    #pragma unroll
    for (int kk = 0; kk < 16; ++kk) {
      float4 a4 = *(const float4*)&As[kk][4 * ty];
      float4 b4 = *(const float4*)&Bs[kk][4 * tx];
      float a[4] = {a4.x, a4.y, a4.z, a4.w};
      float b[4] = {b4.x, b4.y, b4.z, b4.w};
      #pragma unroll
      for (int i = 0; i < 4; ++i)
        #pragma unroll
        for (int j = 0; j < 4; ++j) acc[i][j] = fmaf(a[i], b[j], acc[i][j]);
    }
  }
  float* Pz = P + (size_t)blockIdx.z * M * N;
  #pragma unroll
  for (int i = 0; i < 4; ++i) {
    int m = m0 + 4 * ty + i, n = n0 + 4 * tx;
    if (n < N)
      *(float4*)(Pz + (size_t)m * N + n) = make_float4(acc[i][0], acc[i][1], acc[i][2], acc[i][3]);
  }
}

// h = relu(sum_s part[s] + b_enc); z_mean/z_log_var -> out; z -> dz[0:64]
__global__ __launch_bounds__(128) void mulv_z_kernel(const float* __restrict__ part,
    const float* __restrict__ benc,
    const float* __restrict__ Wmu, const float* __restrict__ bmu,
    const float* __restrict__ Wlv, const float* __restrict__ blv,
    const float* __restrict__ eps, float* __restrict__ out, float* __restrict__ dz) {
  __shared__ __align__(16) float hs[512];
  __shared__ float zms[64], zlvs[64];
  int b = blockIdx.x, t = threadIdx.x;
  for (int i = t; i < 512; i += 128) {
    float a = benc[i];
    #pragma unroll
    for (int s = 0; s < 4; ++s) a += part[(size_t)s * 131072 + b * 512 + i];
    hs[i] = fmaxf(a, 0.f);
  }
  __syncthreads();
  const float* Wr = (t < 64) ? (Wmu + (size_t)t * 512) : (Wlv + (size_t)(t - 64) * 512);
  float bias = (t < 64) ? bmu[t] : blv[t - 64];
  const float4* w4 = (const float4*)Wr;
  const float4* h4 = (const float4*)hs;
  float a0 = 0.f, a1 = 0.f, a2 = 0.f, a3 = 0.f;
  #pragma unroll 4
  for (int i = 0; i < 128; ++i) {
    float4 w = w4[i], hv = h4[i];
    a0 = fmaf(w.x, hv.x, a0); a1 = fmaf(w.y, hv.y, a1);
    a2 = fmaf(w.z, hv.z, a2); a3 = fmaf(w.w, hv.w, a3);
  }
  float acc = (a0 + a1) + (a2 + a3) + bias;
  if (t < 64) { out[OUT_ZM + b * 64 + t] = acc; zms[t] = acc; }
  else        { out[OUT_ZLV + b * 64 + (t - 64)] = acc; zlvs[t - 64] = acc; }
  __syncthreads();
  if (t < 64) {
    float zv = fmaf(eps[b * 64 + t], __builtin_amdgcn_exp2f(0.7213475204444817f * zlvs[t]), zms[t]);
    dz[b * 1104 + t] = zv;
  }
}

// d2 GEMM with reduce-on-load: A[m][k] = relu(sum_s part[s][m*512+k] + b_d1[k]),
// C = relu(A @ W_d2^T + b_d2) * LOG2E -> rx. M=256,N=160,K=512.
__global__ __launch_bounds__(256) void gemm_d2(const float* __restrict__ part,
    const float* __restrict__ bd1, const float* __restrict__ W,
    const float* __restrict__ bias, float* __restrict__ rx) {
  __shared__ float As[16][68];
  __shared__ float Bs[16][68];
  const int N = 160, K = 512;
  int tid = threadIdx.x;
  int m0 = blockIdx.y * 64, n0 = blockIdx.x * 64;
  int sr = tid >> 2, sc = (tid & 3) * 4;
  int tx = tid & 15, ty = tid >> 4;
  float acc[4][4];
  #pragma unroll
  for (int i = 0; i < 4; ++i)
    #pragma unroll
    for (int j = 0; j < 4; ++j) acc[i][j] = 0.f;
  for (int k0 = 0; k0 < K; k0 += 16) {
    int col = k0 + sc;
    const float* p = part + (size_t)(m0 + sr) * 512 + col;
    float4 a0 = *(const float4*)(p);
    float4 a1 = *(const float4*)(p + 131072);
    float4 a2 = *(const float4*)(p + 262144);
    float4 a3 = *(const float4*)(p + 393216);
    float4 bb = *(const float4*)(bd1 + col);
    float4 av;
    av.x = fmaxf(a0.x + a1.x + a2.x + a3.x + bb.x, 0.f);
    av.y = fmaxf(a0.y + a1.y + a2.y + a3.y + bb.y, 0.f);
    av.z = fmaxf(a0.z + a1.z + a2.z + a3.z + bb.z, 0.f);
    av.w = fmaxf(a0.w + a1.w + a2.w + a3.w + bb.w, 0.f);
    float4 bv = make_float4(0.f, 0.f, 0.f, 0.f);
    if (n0 + sr < N)
      bv = *(const float4*)(W + (size_t)(n0 + sr) * 512 + col);
    __syncthreads();
    As[sc][sr] = av.x; As[sc + 1][sr] = av.y; As[sc + 2][sr] = av.z; As[sc + 3][sr] = av.w;
    Bs[sc][sr] = bv.x; Bs[sc + 1][sr] = bv.y; Bs[sc + 2][sr] = bv.z; Bs[sc + 3][sr] = bv.w;
    __syncthreads();
    #pragma unroll
    for (int kk = 0; kk < 16; ++kk) {
      float4 a4 = *(const float4*)&As[kk][4 * ty];
      float4 b4 = *(const float4*)&Bs[kk][4 * tx];
      float a[4] = {a4.x, a4.y, a4.z, a4.w};
      float b[4] = {b4.x, b4.y, b4.z, b4.w};
      #pragma unroll
      for (int i = 0; i < 4; ++i)
        #pragma unroll
        for (int j = 0; j < 4; ++j) acc[i][j] = fmaf(a[i], b[j], acc[i][j]);
    }
  }
  #pragma unroll
  for (int i = 0; i < 4; ++i) {
    int m = m0 + 4 * ty + i, n = n0 + 4 * tx;
    if (n < N) {
      float4 v;
      v.x = fmaxf(acc[i][0] + bias[n], 0.f) * LOG2E;
      v.y = fmaxf(acc[i][1] + bias[n + 1], 0.f) * LOG2E;
      v.z = fmaxf(acc[i][2] + bias[n + 2], 0.f) * LOG2E;
      v.w = fmaxf(acc[i][3] + bias[n + 3], 0.f) * LOG2E;
      *(float4*)(rx + (size_t)m * 160 + n) = v;
    }
  }
}

// Per (b, chunk): fixed-shift softmax partials. rx pre-scaled by LOG2E.
// 2 items per macro-iter (e[2][4]=32 VGPR live) amortize rxs LDS broadcast 2x.
// launch_bounds(256,2): round-3-verified no-spill config. DO NOT raise to 3 —
// round 4 showed that forces a 620 MB scratch spill (84 VGPR, 5x regression).
__global__ __launch_bounds__(256, 2) void score_part(const float* __restrict__ rx,
    const float* __restrict__ emb, float* __restrict__ psg, float* __restrict__ pmg,
    int* __restrict__ pag) {
  __shared__ __align__(16) float rxs[160];
  __shared__ float wm[4][10], wsum[4][10];
  __shared__ int wa[4][10];
  int b = blockIdx.x, c = blockIdx.y, t = threadIdx.x;
  if (t < 160) rxs[t] = rx[b * 160 + t];
  __syncthreads();
  float m[10], s[10];
  int am[10];
  #pragma unroll
  for (int k = 0; k < 10; ++k) { m[k] = -3.402823466e38f; s[k] = 0.f; am[k] = 0; }
  int nBase = c * CHUNK;
  const float4* ep = (const float4*)emb;
  #pragma unroll 1
  for (int j = 0; j < 12; ++j) {
    int n0 = nBase + j * 512 + t;
    float4 e[2][4];
    #pragma unroll
    for (int it = 0; it < 2; ++it) {
      const float4* p = ep + (size_t)(n0 + it * 256) * 4;
      e[it][0] = p[0]; e[it][1] = p[1]; e[it][2] = p[2]; e[it][3] = p[3];
    }
    #pragma unroll
    for (int k = 0; k < 10; ++k) {
      float4 r0 = *(const float4*)(rxs + k * 16);
      float4 r1 = *(const float4*)(rxs + k * 16 + 4);
      float4 r2 = *(const float4*)(rxs + k * 16 + 8);
      float4 r3 = *(const float4*)(rxs + k * 16 + 12);
      #pragma unroll
      for (int it = 0; it < 2; ++it) {
        float x0 = fmaf(e[it][0].x, r0.x, -SHIFT);
        float x1 = e[it][1].x * r1.x;
        float x2 = e[it][2].x * r2.x;
        float x3 = e[it][3].x * r3.x;
        x0 = fmaf(e[it][0].y, r0.y, x0);
        x1 = fmaf(e[it][1].y, r1.y, x1);
        x2 = fmaf(e[it][2].y, r2.y, x2);
        x3 = fmaf(e[it][3].y, r3.y, x3);
        x0 = fmaf(e[it][0].z, r0.z, x0);
        x1 = fmaf(e[it][1].z, r1.z, x1);
        x2 = fmaf(e[it][2].z, r2.z, x2);
        x3 = fmaf(e[it][3].z, r3.z, x3);
        x0 = fmaf(e[it][0].w, r0.w, x0);
        x1 = fmaf(e[it][1].w, r1.w, x1);
        x2 = fmaf(e[it][2].w, r2.w, x2);
        x3 = fmaf(e[it][3].w, r3.w, x3);
        float x = (x0 + x1) + (x2 + x3);
        s[k] += __builtin_amdgcn_exp2f(x);
        if (x > m[k]) { m[k] = x; am[k] = n0 + it * 256; }
      }
    }
  }
  // tail: 106 items
  if (t < CHUNK - 6144) {
    int n = nBase + 6144 + t;
    const float4* p = ep + (size_t)n * 4;
    float4 e0 = p[0], e1 = p[1], e2 = p[2], e3 = p[3];
    #pragma unroll
    for (int k = 0; k < 10; ++k) {
      const float4 r0 = *(const float4*)(rxs + k * 16);
      const float4 r1 = *(const float4*)(rxs + k * 16 + 4);
      const float4 r2 = *(const float4*)(rxs + k * 16 + 8);
      const float4 r3 = *(const float4*)(rxs + k * 16 + 12);
      float x0 = fmaf(e0.w, r0.w, fmaf(e0.z, r0.z, fmaf(e0.y, r0.y, fmaf(e0.x, r0.x, -SHIFT))));
      float x1 = fmaf(e1.w, r1.w, fmaf(e1.z, r1.z, fmaf(e1.y, r1.y, e1.x * r1.x)));
      float x2 = fmaf(e2.w, r2.w, fmaf(e2.z, r2.z, fmaf(e2.y, r2.y, e2.x * r2.x)));
      float x3 = fmaf(e3.w, r3.w, fmaf(e3.z, r3.z, fmaf(e3.y, r3.y, e3.x * r3.x)));
      float x = (x0 + x1) + (x2 + x3);
      s[k] += __builtin_amdgcn_exp2f(x);
      if (x > m[k]) { m[k] = x; am[k] = n; }
    }
  }
  // wave reduce: s sums; (m, am) argmax, lower index wins ties
  #pragma unroll
  for (int off = 32; off > 0; off >>= 1) {
    #pragma unroll
    for (int k = 0; k < 10; ++k) {
      s[k] += __shfl_down(s[k], off);
      float om = __shfl_down(m[k], off);
      int oa = __shfl_down(am[k], off);
      bool take = (om > m[k]) || (om == m[k] && oa < am[k]);
      am[k] = take ? oa : am[k];
      m[k] = fmaxf(m[k], om);
    }
  }
  int lane = t & 63, wv = t >> 6;
  if (lane == 0) {
    #pragma unroll
    for (int k = 0; k < 10; ++k) { wm[wv][k] = m[k]; wsum[wv][k] = s[k]; wa[wv][k] = am[k]; }
  }
  __syncthreads();
  if (t < 10) {
    int k = t;
    float M = wm[0][k], S = wsum[0][k];
    int AM = wa[0][k];
    #pragma unroll
    for (int w = 1; w < 4; ++w) {
      float m2 = wm[w][k];
      int oa = wa[w][k];
      bool take = (m2 > M) || (m2 == M && oa < AM);
      AM = take ? oa : AM;
      M = fmaxf(M, m2);
      S += wsum[w][k];
    }
    int idx = (b * NCHUNK + c) * 10 + k;
    psg[idx] = S; pmg[idx] = M; pag[idx] = AM;
  }
}

// Combine chunk partials: S adds (shared fixed shift); argmax; slate prob.
__global__ __launch_bounds__(256) void score_final(const float* __restrict__ psg,
    const float* __restrict__ pmg, const int* __restrict__ pag,
    const float* __restrict__ rx, const float* __restrict__ emb,
    const int* __restrict__ slate, float* __restrict__ out) {
  int tid = blockIdx.x * 256 + threadIdx.x;
  if (tid >= BATCH * 10) return;
  int b = tid / 10, k = tid % 10;
  int base = b * NCHUNK * 10 + k;
  float S = 0.f, M = -3.402823466e38f;
  int AM = 2147483647;
  #pragma unroll
  for (int c = 0; c < NCHUNK; ++c) {
    S += psg[base + c * 10];
    float m2 = pmg[base + c * 10];
    int oa = pag[base + c * 10];
    bool take = (m2 > M) || (m2 == M && oa < AM);
    AM = take ? oa : AM;
    M = fmaxf(M, m2);
  }
  int it = slate[b * 10 + k];
  const float* er = emb + (size_t)it * 16;
  const float* rr = rx + b * 160 + k * 16;
  float xs = -SHIFT;
  #pragma unroll
  for (int e = 0; e < 16; ++e) xs = fmaf(rr[e], er[e], xs);
  out[OUT_RS + b * 10 + k] = (float)AM;
  out[OUT_RR + b * 10 + k] = __builtin_amdgcn_exp2f(xs) / S;
}

extern "C" void kernel_launch(void* const* d_in, const int* in_sizes, int n_in,
                              void* d_out, int out_size, void* d_ws, size_t ws_size,
                              hipStream_t stream) {
  const int* user_repr = (const int*)d_in[0];
  const int* slate = (const int*)d_in[1];
  const float* resp = (const float*)d_in[2];
  const float* eps = (const float*)d_in[3];
  const float* emb = (const float*)d_in[4];
  const float* W_enc = (const float*)d_in[5];
  const float* b_enc = (const float*)d_in[6];
  const float* W_mu = (const float*)d_in[7];
  const float* b_mu = (const float*)d_in[8];
  const float* W_lv = (const float*)d_in[9];
  const float* b_lv = (const float*)d_in[10];
  const float* W_d1 = (const float*)d_in[11];
  const float* b_d1 = (const float*)d_in[12];
  const float* W_d2 = (const float*)d_in[13];
  const float* b_d2 = (const float*)d_in[14];
  float* out = (float*)d_out;
  float* ws = (float*)d_ws;

  float* x    = ws + WS_X;
  float* dz   = ws + WS_DZ;
  float* rx   = ws + WS_RX;
  float* part = ws + WS_PART;
  float* sps  = ws + WS_SPS;
  float* spm  = ws + WS_SPM;
  int*   spa  = (int*)(ws + WS_SPA);

  pool_build<<<256, 256, 0, stream>>>(user_repr, slate, resp, emb, x, dz);
  gemm64<<<dim3(8, 4, 4), 256, 0, stream>>>(x, W_enc, part, 256, 512, 1200, 300);
  mulv_z_kernel<<<256, 128, 0, stream>>>(part, b_enc, W_mu, b_mu, W_lv, b_lv, eps, out, dz);
  gemm64<<<dim3(8, 4, 4), 256, 0, stream>>>(dz, W_d1, part, 256, 512, 1104, 276);
  gemm_d2<<<dim3(3, 4), 256, 0, stream>>>(part, b_d1, W_d2, b_d2, rx);
  score_part<<<dim3(256, 8), 256, 0, stream>>>(rx, emb, sps, spm, spa);
  score_final<<<10, 256, 0, stream>>>(sps, spm, spa, rx, emb, slate, out);
}

// Round 6
// 323.481 us; speedup vs baseline: 2.9869x; 1.3104x over previous
//
#include <hip/hip_runtime.h>

// Problem constants
#define NITEMS 50000
#define EMBD   16
#define NSLATE 10
#define HIDD   512
#define LATD   64
#define RESPD  1024
#define BATCH  256
#define NCHUNK 8
#define CHUNK  6250   // score: NITEMS/8; 6250 = 12*512 + 106
#define PCHUNK 3125   // pool: NITEMS/16; 3125 = 12*256 + 53
#define LOG2E  1.44269504088896340736f
#define SHIFT  64.0f  // fixed log2-domain shift: s = sum exp2(x*log2e - 64)

// d_out layout (float): z_mean[256*64] | z_log_var[256*64] | recon_slate[256*10] | recon_resp[256*10]
#define OUT_ZM 0
#define OUT_ZLV 16384
#define OUT_RS 32768
#define OUT_RR 35328

// ws layout (floats), with time-overlays (all dispatches are stream-ordered):
//   [0 .. 589824)        x[307200] + dz[282624]   (live: build_x -> enc / d1)
//                        OVERLAY p2[8*40960=327680] (live: gemm_d2 -> score; x,dz dead by then)
//   [589824 .. 868352)   pool partials pp[256*64*17=278528] (live: pool_part -> build_x)
//   [589824 .. 1114112)  OVERLAY part[4*131072=524288] (live: enc->mulv_z, d1->gemm_d2; pp dead)
//   [1114112 .. 1155072) rx[40960]
//   [1155072 .. 1216512) sps/spm/spa [3*20480]
// total 1216512 floats = 4.87 MB (same as round-5 known-safe footprint)
#define WS_X    0
#define WS_DZ   307200
#define WS_P2   0
#define WS_PP   589824
#define WS_PART 589824
#define WS_RX   1114112
#define WS_SPS  1155072
#define WS_SPM  1175552
#define WS_SPA  1196032

// Pool partials: grid (256 b, 16 c). Per-wave 17-float partial -> pp, no atomics.
__global__ __launch_bounds__(256) void pool_part(const int* __restrict__ u,
    const float* __restrict__ emb, float* __restrict__ pp) {
  int b = blockIdx.x, c = blockIdx.y, t = threadIdx.x;
  float acc[16];
  #pragma unroll
  for (int i = 0; i < 16; ++i) acc[i] = 0.0f;
  float cnt = 0.0f;
  const int* ub = u + (size_t)b * NITEMS;
  int n1 = c * PCHUNK + PCHUNK;
  for (int n = c * PCHUNK + t; n < n1; n += 256) {
    if (ub[n]) {
      const float4* e4 = (const float4*)(emb + (size_t)n * 16);
      float4 a = e4[0], bb = e4[1], cc = e4[2], dd = e4[3];
      acc[0] += a.x;  acc[1] += a.y;  acc[2] += a.z;  acc[3] += a.w;
      acc[4] += bb.x; acc[5] += bb.y; acc[6] += bb.z; acc[7] += bb.w;
      acc[8] += cc.x; acc[9] += cc.y; acc[10] += cc.z; acc[11] += cc.w;
      acc[12] += dd.x; acc[13] += dd.y; acc[14] += dd.z; acc[15] += dd.w;
      cnt += 1.0f;
    }
  }
  #pragma unroll
  for (int off = 32; off > 0; off >>= 1) {
    #pragma unroll
    for (int i = 0; i < 16; ++i) acc[i] += __shfl_down(acc[i], off);
    cnt += __shfl_down(cnt, off);
  }
  int lane = t & 63, wv = t >> 6;
  if (lane == 0) {
    float* dst = pp + ((size_t)(b * 16 + c) * 4 + wv) * 17;
    #pragma unroll
    for (int i = 0; i < 16; ++i) dst[i] = acc[i];
    dst[16] = cnt;
  }
}

// Sum 64 wave-partials per b; build x = [slate(160)|user(16)|resp(1024)],
// dz[64:1104] = [user|resp].
__global__ __launch_bounds__(256) void build_x(const float* __restrict__ pp,
    const int* __restrict__ slate, const float* __restrict__ resp,
    const float* __restrict__ emb, float* __restrict__ x, float* __restrict__ dz) {
  __shared__ float fin[17];
  int b = blockIdx.x, t = threadIdx.x;
  if (t < 17) {
    float a = 0.f;
    const float* p = pp + (size_t)b * 64 * 17 + t;
    #pragma unroll
    for (int w = 0; w < 64; ++w) a += p[w * 17];
    fin[t] = a;
  }
  __syncthreads();
  float inv = 1.0f / fin[16];
  if (t < 16) {
    float uv = fin[t] * inv;
    x[b * 1200 + 160 + t] = uv;
    dz[b * 1104 + 64 + t] = uv;
  }
  if (t >= 32 && t < 192) {
    int i = t - 32;
    int k = i >> 4, e = i & 15;
    int it = slate[b * 10 + k];
    x[b * 1200 + i] = emb[(size_t)it * 16 + e];
  }
  for (int i = t; i < 1024; i += 256) {
    float r = resp[b * 1024 + i];
    x[b * 1200 + 176 + i] = r;
    dz[b * 1104 + 80 + i] = r;
  }
}

// Split-K partial GEMM: P[z][M,N] = A[M,ks:ke] @ B[N,ks:ke]^T
__global__ __launch_bounds__(256) void gemm64(const float* __restrict__ A,
    const float* __restrict__ B, float* __restrict__ P, int M, int N, int K, int kChunk) {
  __shared__ float As[16][68];  // As[kk][m]
  __shared__ float Bs[16][68];  // Bs[kk][n]
  int tid = threadIdx.x;
  int m0 = blockIdx.y * 64, n0 = blockIdx.x * 64;
  int ks = blockIdx.z * kChunk;
  int ke = ks + kChunk; if (ke > K) ke = K;
  int sr = tid >> 2;          // 0..63
  int sc = (tid & 3) * 4;     // 0,4,8,12
  int tx = tid & 15, ty = tid >> 4;
  float acc[4][4];
  #pragma unroll
  for (int i = 0; i < 4; ++i)
    #pragma unroll
    for (int j = 0; j < 4; ++j) acc[i][j] = 0.f;
  for (int k0 = ks; k0 < ke; k0 += 16) {
    float4 av = make_float4(0.f, 0.f, 0.f, 0.f);
    float4 bv = make_float4(0.f, 0.f, 0.f, 0.f);
    if (k0 + sc < ke)
      av = *(const float4*)(A + (size_t)(m0 + sr) * K + k0 + sc);
    if (k0 + sc < ke && n0 + sr < N)
      bv = *(const float4*)(B + (size_t)(n0 + sr) * K + k0 + sc);
    __syncthreads();
    As[sc][sr] = av.x; As[sc + 1][sr] = av.y; As[sc + 2][sr] = av.z; As[sc + 3][sr] = av.w;
    Bs[sc][sr] = bv.x; Bs[sc + 1][sr] = bv.y; Bs[sc + 2][sr] = bv.z; Bs[sc + 3][sr] = bv.w;
    __syncthreads();
    #pragma unroll
    for (int kk = 0; kk < 16; ++kk) {
      float4 a4 = *(const float4*)&As[kk][4 * ty];
      float4 b4 = *(const float4*)&Bs[kk][4 * tx];
      float a[4] = {a4.x, a4.y, a4.z, a4.w};
      float b[4] = {b4.x, b4.y, b4.z, b4.w};
      #pragma unroll
      for (int i = 0; i < 4; ++i)
        #pragma unroll
        for (int j = 0; j < 4; ++j) acc[i][j] = fmaf(a[i], b[j], acc[i][j]);
    }
  }
  float* Pz = P + (size_t)blockIdx.z * M * N;
  #pragma unroll
  for (int i = 0; i < 4; ++i) {
    int m = m0 + 4 * ty + i, n = n0 + 4 * tx;
    if (n < N)
      *(float4*)(Pz + (size_t)m * N + n) = make_float4(acc[i][0], acc[i][1], acc[i][2], acc[i][3]);
  }
}

// h = relu(sum_s part[s] + b_enc); z_mean/z_log_var -> out; z -> dz[0:64]
__global__ __launch_bounds__(128) void mulv_z_kernel(const float* __restrict__ part,
    const float* __restrict__ benc,
    const float* __restrict__ Wmu, const float* __restrict__ bmu,
    const float* __restrict__ Wlv, const float* __restrict__ blv,
    const float* __restrict__ eps, float* __restrict__ out, float* __restrict__ dz) {
  __shared__ __align__(16) float hs[512];
  __shared__ float zms[64], zlvs[64];
  int b = blockIdx.x, t = threadIdx.x;
  for (int i = t; i < 512; i += 128) {
    float a = benc[i];
    #pragma unroll
    for (int s = 0; s < 4; ++s) a += part[(size_t)s * 131072 + b * 512 + i];
    hs[i] = fmaxf(a, 0.f);
  }
  __syncthreads();
  const float* Wr = (t < 64) ? (Wmu + (size_t)t * 512) : (Wlv + (size_t)(t - 64) * 512);
  float bias = (t < 64) ? bmu[t] : blv[t - 64];
  const float4* w4 = (const float4*)Wr;
  const float4* h4 = (const float4*)hs;
  float a0 = 0.f, a1 = 0.f, a2 = 0.f, a3 = 0.f;
  #pragma unroll 4
  for (int i = 0; i < 128; ++i) {
    float4 w = w4[i], hv = h4[i];
    a0 = fmaf(w.x, hv.x, a0); a1 = fmaf(w.y, hv.y, a1);
    a2 = fmaf(w.z, hv.z, a2); a3 = fmaf(w.w, hv.w, a3);
  }
  float acc = (a0 + a1) + (a2 + a3) + bias;
  if (t < 64) { out[OUT_ZM + b * 64 + t] = acc; zms[t] = acc; }
  else        { out[OUT_ZLV + b * 64 + (t - 64)] = acc; zlvs[t - 64] = acc; }
  __syncthreads();
  if (t < 64) {
    float zv = fmaf(eps[b * 64 + t], __builtin_amdgcn_exp2f(0.7213475204444817f * zlvs[t]), zms[t]);
    dz[b * 1104 + t] = zv;
  }
}

// d2 split-K GEMM with reduce-on-load: A[m][k] = relu(sum_s part[s][m*512+k] + b_d1[k]),
// P2[z] = A[:, z*64:(z+1)*64] @ W_d2[:, same]^T. Grid (3,4,8). Bias/relu/scale in score preamble.
__global__ __launch_bounds__(256) void gemm_d2(const float* __restrict__ part,
    const float* __restrict__ bd1, const float* __restrict__ W, float* __restrict__ p2) {
  __shared__ float As[16][68];
  __shared__ float Bs[16][68];
  const int N = 160;
  int tid = threadIdx.x;
  int m0 = blockIdx.y * 64, n0 = blockIdx.x * 64;
  int ks = blockIdx.z * 64, ke = ks + 64;
  int sr = tid >> 2, sc = (tid & 3) * 4;
  int tx = tid & 15, ty = tid >> 4;
  float acc[4][4];
  #pragma unroll
  for (int i = 0; i < 4; ++i)
    #pragma unroll
    for (int j = 0; j < 4; ++j) acc[i][j] = 0.f;
  for (int k0 = ks; k0 < ke; k0 += 16) {
    int col = k0 + sc;
    const float* p = part + (size_t)(m0 + sr) * 512 + col;
    float4 a0 = *(const float4*)(p);
    float4 a1 = *(const float4*)(p + 131072);
    float4 a2 = *(const float4*)(p + 262144);
    float4 a3 = *(const float4*)(p + 393216);
    float4 bb = *(const float4*)(bd1 + col);
    float4 av;
    av.x = fmaxf(a0.x + a1.x + a2.x + a3.x + bb.x, 0.f);
    av.y = fmaxf(a0.y + a1.y + a2.y + a3.y + bb.y, 0.f);
    av.z = fmaxf(a0.z + a1.z + a2.z + a3.z + bb.z, 0.f);
    av.w = fmaxf(a0.w + a1.w + a2.w + a3.w + bb.w, 0.f);
    float4 bv = make_float4(0.f, 0.f, 0.f, 0.f);
    if (n0 + sr < N)
      bv = *(const float4*)(W + (size_t)(n0 + sr) * 512 + col);
    __syncthreads();
    As[sc][sr] = av.x; As[sc + 1][sr] = av.y; As[sc + 2][sr] = av.z; As[sc + 3][sr] = av.w;
    Bs[sc][sr] = bv.x; Bs[sc + 1][sr] = bv.y; Bs[sc + 2][sr] = bv.z; Bs[sc + 3][sr] = bv.w;
    __syncthreads();
    #pragma unroll
    for (int kk = 0; kk < 16; ++kk) {
      float4 a4 = *(const float4*)&As[kk][4 * ty];
      float4 b4 = *(const float4*)&Bs[kk][4 * tx];
      float a[4] = {a4.x, a4.y, a4.z, a4.w};
      float b[4] = {b4.x, b4.y, b4.z, b4.w};
      #pragma unroll
      for (int i = 0; i < 4; ++i)
        #pragma unroll
        for (int j = 0; j < 4; ++j) acc[i][j] = fmaf(a[i], b[j], acc[i][j]);
    }
  }
  float* Pz = p2 + (size_t)blockIdx.z * 40960;
  #pragma unroll
  for (int i = 0; i < 4; ++i) {
    int m = m0 + 4 * ty + i, n = n0 + 4 * tx;
    if (n < N)
      *(float4*)(Pz + (size_t)m * 160 + n) = make_float4(acc[i][0], acc[i][1], acc[i][2], acc[i][3]);
  }
}

// Per (b, chunk): fixed-shift softmax partials. Preamble finishes d2:
// rxs = relu(sum_z p2[z] + b_d2) * LOG2E; chunk-0 block publishes rx for score_final.
// 2 items per macro-iter (e[2][4]=32 VGPR live) amortize rxs LDS broadcast 2x.
// launch_bounds(256,2): round-3-verified no-spill config. DO NOT raise to 3 —
// round 4 showed that forces a 620 MB scratch spill (84 VGPR, 5x regression).
__global__ __launch_bounds__(256, 2) void score_part(const float* __restrict__ p2,
    const float* __restrict__ bd2, const float* __restrict__ emb,
    float* __restrict__ rx, float* __restrict__ psg, float* __restrict__ pmg,
    int* __restrict__ pag) {
  __shared__ __align__(16) float rxs[160];
  __shared__ float wm[4][10], wsum[4][10];
  __shared__ int wa[4][10];
  int b = blockIdx.x, c = blockIdx.y, t = threadIdx.x;
  if (t < 160) {
    float a = bd2[t];
    #pragma unroll
    for (int z = 0; z < 8; ++z) a += p2[(size_t)z * 40960 + b * 160 + t];
    float v = fmaxf(a, 0.f) * LOG2E;
    rxs[t] = v;
    if (c == 0) rx[b * 160 + t] = v;
  }
  __syncthreads();
  float m[10], s[10];
  int am[10];
  #pragma unroll
  for (int k = 0; k < 10; ++k) { m[k] = -3.402823466e38f; s[k] = 0.f; am[k] = 0; }
  int nBase = c * CHUNK;
  const float4* ep = (const float4*)emb;
  #pragma unroll 1
  for (int j = 0; j < 12; ++j) {
    int n0 = nBase + j * 512 + t;
    float4 e[2][4];
    #pragma unroll
    for (int it = 0; it < 2; ++it) {
      const float4* p = ep + (size_t)(n0 + it * 256) * 4;
      e[it][0] = p[0]; e[it][1] = p[1]; e[it][2] = p[2]; e[it][3] = p[3];
    }
    #pragma unroll
    for (int k = 0; k < 10; ++k) {
      float4 r0 = *(const float4*)(rxs + k * 16);
      float4 r1 = *(const float4*)(rxs + k * 16 + 4);
      float4 r2 = *(const float4*)(rxs + k * 16 + 8);
      float4 r3 = *(const float4*)(rxs + k * 16 + 12);
      #pragma unroll
      for (int it = 0; it < 2; ++it) {
        float x0 = fmaf(e[it][0].x, r0.x, -SHIFT);
        float x1 = e[it][1].x * r1.x;
        float x2 = e[it][2].x * r2.x;
        float x3 = e[it][3].x * r3.x;
        x0 = fmaf(e[it][0].y, r0.y, x0);
        x1 = fmaf(e[it][1].y, r1.y, x1);
        x2 = fmaf(e[it][2].y, r2.y, x2);
        x3 = fmaf(e[it][3].y, r3.y, x3);
        x0 = fmaf(e[it][0].z, r0.z, x0);
        x1 = fmaf(e[it][1].z, r1.z, x1);
        x2 = fmaf(e[it][2].z, r2.z, x2);
        x3 = fmaf(e[it][3].z, r3.z, x3);
        x0 = fmaf(e[it][0].w, r0.w, x0);
        x1 = fmaf(e[it][1].w, r1.w, x1);
        x2 = fmaf(e[it][2].w, r2.w, x2);
        x3 = fmaf(e[it][3].w, r3.w, x3);
        float x = (x0 + x1) + (x2 + x3);
        s[k] += __builtin_amdgcn_exp2f(x);
        if (x > m[k]) { m[k] = x; am[k] = n0 + it * 256; }
      }
    }
  }
  // tail: 106 items
  if (t < CHUNK - 6144) {
    int n = nBase + 6144 + t;
    const float4* p = ep + (size_t)n * 4;
    float4 e0 = p[0], e1 = p[1], e2 = p[2], e3 = p[3];
    #pragma unroll
    for (int k = 0; k < 10; ++k) {
      const float4 r0 = *(const float4*)(rxs + k * 16);
      const float4 r1 = *(const float4*)(rxs + k * 16 + 4);
      const float4 r2 = *(const float4*)(rxs + k * 16 + 8);
      const float4 r3 = *(const float4*)(rxs + k * 16 + 12);
      float x0 = fmaf(e0.w, r0.w, fmaf(e0.z, r0.z, fmaf(e0.y, r0.y, fmaf(e0.x, r0.x, -SHIFT))));
      float x1 = fmaf(e1.w, r1.w, fmaf(e1.z, r1.z, fmaf(e1.y, r1.y, e1.x * r1.x)));
      float x2 = fmaf(e2.w, r2.w, fmaf(e2.z, r2.z, fmaf(e2.y, r2.y, e2.x * r2.x)));
      float x3 = fmaf(e3.w, r3.w, fmaf(e3.z, r3.z, fmaf(e3.y, r3.y, e3.x * r3.x)));
      float x = (x0 + x1) + (x2 + x3);
      s[k] += __builtin_amdgcn_exp2f(x);
      if (x > m[k]) { m[k] = x; am[k] = n; }
    }
  }
  // wave reduce: s sums; (m, am) argmax, lower index wins ties
  #pragma unroll
  for (int off = 32; off > 0; off >>= 1) {
    #pragma unroll
    for (int k = 0; k < 10; ++k) {
      s[k] += __shfl_down(s[k], off);
      float om = __shfl_down(m[k], off);
      int oa = __shfl_down(am[k], off);
      bool take = (om > m[k]) || (om == m[k] && oa < am[k]);
      am[k] = take ? oa : am[k];
      m[k] = fmaxf(m[k], om);
    }
  }
  int lane = t & 63, wv = t >> 6;
  if (lane == 0) {
    #pragma unroll
    for (int k = 0; k < 10; ++k) { wm[wv][k] = m[k]; wsum[wv][k] = s[k]; wa[wv][k] = am[k]; }
  }
  __syncthreads();
  if (t < 10) {
    int k = t;
    float M = wm[0][k], S = wsum[0][k];
    int AM = wa[0][k];
    #pragma unroll
    for (int w = 1; w < 4; ++w) {
      float m2 = wm[w][k];
      int oa = wa[w][k];
      bool take = (m2 > M) || (m2 == M && oa < AM);
      AM = take ? oa : AM;
      M = fmaxf(M, m2);
      S += wsum[w][k];
    }
    int idx = (b * NCHUNK + c) * 10 + k;
    psg[idx] = S; pmg[idx] = M; pag[idx] = AM;
  }
}

// Combine chunk partials: S adds (shared fixed shift); argmax; slate prob.
__global__ __launch_bounds__(256) void score_final(const float* __restrict__ psg,
    const float* __restrict__ pmg, const int* __restrict__ pag,
    const float* __restrict__ rx, const float* __restrict__ emb,
    const int* __restrict__ slate, float* __restrict__ out) {
  int tid = blockIdx.x * 256 + threadIdx.x;
  if (tid >= BATCH * 10) return;
  int b = tid / 10, k = tid % 10;
  int base = b * NCHUNK * 10 + k;
  float S = 0.f, M = -3.402823466e38f;
  int AM = 2147483647;
  #pragma unroll
  for (int c = 0; c < NCHUNK; ++c) {
    S += psg[base + c * 10];
    float m2 = pmg[base + c * 10];
    int oa = pag[base + c * 10];
    bool take = (m2 > M) || (m2 == M && oa < AM);
    AM = take ? oa : AM;
    M = fmaxf(M, m2);
  }
  int it = slate[b * 10 + k];
  const float* er = emb + (size_t)it * 16;
  const float* rr = rx + b * 160 + k * 16;  // pre-scaled by LOG2E
  float xs = -SHIFT;
  #pragma unroll
  for (int e = 0; e < 16; ++e) xs = fmaf(rr[e], er[e], xs);
  out[OUT_RS + b * 10 + k] = (float)AM;
  out[OUT_RR + b * 10 + k] = __builtin_amdgcn_exp2f(xs) / S;
}

extern "C" void kernel_launch(void* const* d_in, const int* in_sizes, int n_in,
                              void* d_out, int out_size, void* d_ws, size_t ws_size,
                              hipStream_t stream) {
  const int* user_repr = (const int*)d_in[0];
  const int* slate = (const int*)d_in[1];
  const float* resp = (const float*)d_in[2];
  const float* eps = (const float*)d_in[3];
  const float* emb = (const float*)d_in[4];
  const float* W_enc = (const float*)d_in[5];
  const float* b_enc = (const float*)d_in[6];
  const float* W_mu = (const float*)d_in[7];
  const float* b_mu = (const float*)d_in[8];
  const float* W_lv = (const float*)d_in[9];
  const float* b_lv = (const float*)d_in[10];
  const float* W_d1 = (const float*)d_in[11];
  const float* b_d1 = (const float*)d_in[12];
  const float* W_d2 = (const float*)d_in[13];
  const float* b_d2 = (const float*)d_in[14];
  float* out = (float*)d_out;
  float* ws = (float*)d_ws;

  float* x    = ws + WS_X;
  float* dz   = ws + WS_DZ;
  float* p2   = ws + WS_P2;
  float* pp   = ws + WS_PP;
  float* part = ws + WS_PART;
  float* rx   = ws + WS_RX;
  float* sps  = ws + WS_SPS;
  float* spm  = ws + WS_SPM;
  int*   spa  = (int*)(ws + WS_SPA);

  pool_part<<<dim3(256, 16), 256, 0, stream>>>(user_repr, emb, pp);
  build_x<<<256, 256, 0, stream>>>(pp, slate, resp, emb, x, dz);
  gemm64<<<dim3(8, 4, 4), 256, 0, stream>>>(x, W_enc, part, 256, 512, 1200, 300);
  mulv_z_kernel<<<256, 128, 0, stream>>>(part, b_enc, W_mu, b_mu, W_lv, b_lv, eps, out, dz);
  gemm64<<<dim3(8, 4, 4), 256, 0, stream>>>(dz, W_d1, part, 256, 512, 1104, 276);
  gemm_d2<<<dim3(3, 4, 8), 256, 0, stream>>>(part, b_d1, W_d2, p2);
  score_part<<<dim3(256, 8), 256, 0, stream>>>(p2, b_d2, emb, rx, sps, spm, spa);
  score_final<<<10, 256, 0, stream>>>(sps, spm, spa, rx, emb, slate, out);
}